// Round 1
// baseline (441.237 us; speedup 1.0000x reference)
//
#include <hip/hip_runtime.h>
#include <hip/hip_bf16.h>
#include <cstdint>
#include <cstddef>

#define B_ 4
#define S_ 2048
#define D_ 1024
#define H_ 16
#define DK_ 64
#define NTOK (B_*S_)

typedef __bf16 bf16;
typedef __bf16 bf16x8 __attribute__((ext_vector_type(8)));
typedef float f32x4 __attribute__((ext_vector_type(4)));

// ---------------- fp32 -> bf16 convert (vectorized) ----------------
__global__ void cvt_f32_bf16(const float* __restrict__ src, bf16* __restrict__ dst, int n8) {
    int i = blockIdx.x * blockDim.x + threadIdx.x;
    if (i >= n8) return;
    const float4* s4 = reinterpret_cast<const float4*>(src) + (size_t)i * 2;
    float4 a = s4[0], b = s4[1];
    bf16x8 o;
    o[0] = (bf16)a.x; o[1] = (bf16)a.y; o[2] = (bf16)a.z; o[3] = (bf16)a.w;
    o[4] = (bf16)b.x; o[5] = (bf16)b.y; o[6] = (bf16)b.z; o[7] = (bf16)b.w;
    reinterpret_cast<bf16x8*>(dst)[i] = o;
}

// ---------------- RoPE cos/sin table: [NTOK][32] float2 ----------------
__global__ void rope_table(const int* __restrict__ pos, float2* __restrict__ tab) {
    int i = blockIdx.x * blockDim.x + threadIdx.x;
    if (i >= NTOK * 32) return;
    int n = i >> 5, p = i & 31;
    float pf = (float)pos[n];
    float freq = powf(10000.0f, -(float)p * (1.0f / 32.0f));
    float ang = pf * freq;
    float s, c;
    sincosf(ang, &s, &c);
    tab[i] = make_float2(c, s);
}

// ---------------- GEMM C = A @ Bw^T  (A:[M][1024] bf16, Bw:[1024][1024] bf16 row-major) ----
// MODE 0: bf16 out, plain. MODE 1: bf16 out with fused RoPE. MODE 2: fp32 out.
// 128x128 tile, BK=32, 4 waves, m97 structure with global_load_lds width 16.
template<int MODE>
__global__ __launch_bounds__(256)
void gemm_bt(const bf16* __restrict__ A, const bf16* __restrict__ Bw,
             void* __restrict__ Cp, const float2* __restrict__ tab) {
    constexpr int K = 1024, N = 1024;
    __shared__ bf16 As[128 * 32];
    __shared__ bf16 Bs[128 * 32];
    const int tid = threadIdx.x;
    const int lane = tid & 63;
    const int w = tid >> 6;
    const int wr = w >> 1, wc = w & 1;
    const int m0 = blockIdx.x * 128;
    const int n0 = blockIdx.y * 128;
    const int lr = lane & 15, lg = lane >> 4;

    f32x4 acc[4][4] = {};

    for (int kt = 0; kt < K / 32; ++kt) {
        __syncthreads();
#pragma unroll
        for (int i = 0; i < 2; ++i) {
            int eoff = (i * 256 + tid) * 8;
            int r = eoff >> 5, c = eoff & 31;
            __builtin_amdgcn_global_load_lds(
                (const __attribute__((address_space(1))) uint32_t*)(&A[(size_t)(m0 + r) * K + kt * 32 + c]),
                (__attribute__((address_space(3))) uint32_t*)(&As[eoff]), 16, 0, 0);
            __builtin_amdgcn_global_load_lds(
                (const __attribute__((address_space(1))) uint32_t*)(&Bw[(size_t)(n0 + r) * K + kt * 32 + c]),
                (__attribute__((address_space(3))) uint32_t*)(&Bs[eoff]), 16, 0, 0);
        }
        __syncthreads();
        bf16x8 af[4], bfr[4];
#pragma unroll
        for (int m = 0; m < 4; ++m)
            af[m] = *reinterpret_cast<const bf16x8*>(&As[(wr * 64 + m * 16 + lr) * 32 + lg * 8]);
#pragma unroll
        for (int n = 0; n < 4; ++n)
            bfr[n] = *reinterpret_cast<const bf16x8*>(&Bs[(wc * 64 + n * 16 + lr) * 32 + lg * 8]);
#pragma unroll
        for (int m = 0; m < 4; ++m)
#pragma unroll
            for (int n = 0; n < 4; ++n)
                acc[m][n] = __builtin_amdgcn_mfma_f32_16x16x32_bf16(af[m], bfr[n], acc[m][n], 0, 0, 0);
    }

    // epilogue: C layout col=lane&15, row=(lane>>4)*4+reg
#pragma unroll
    for (int mt = 0; mt < 4; ++mt) {
#pragma unroll
        for (int nt = 0; nt < 4; ++nt) {
#pragma unroll
            for (int r = 0; r < 4; ++r) {
                int row = m0 + wr * 64 + mt * 16 + lg * 4 + r;
                int col = n0 + wc * 64 + nt * 16 + lr;
                float v = acc[mt][nt][r];
                if (MODE == 2) {
                    ((float*)Cp)[(size_t)row * N + col] = v;
                } else if (MODE == 0) {
                    ((bf16*)Cp)[(size_t)row * N + col] = (bf16)v;
                } else {
                    // RoPE: pair (2p, 2p+1) are adjacent cols -> partner is lane^1
                    float partner = __shfl_xor(v, 1, 64);
                    float2 cs = tab[(size_t)row * 32 + ((col >> 1) & 31)];
                    float o = (col & 1) ? fmaf(v, cs.x, partner * cs.y)
                                        : fmaf(v, cs.x, -partner * cs.y);
                    ((bf16*)Cp)[(size_t)row * N + col] = (bf16)o;
                }
            }
        }
    }
}

// ---------------- causal flash attention ----------------
// grid (S/64, B*H), 256 threads = 4 waves, each wave owns 16 q-rows.
// KV tile = 64. K and V^T staged in XOR-swizzled LDS (conflict-free b128 reads).
__global__ __launch_bounds__(256)
void flash_attn(const bf16* __restrict__ Q, const bf16* __restrict__ Kr,
                const bf16* __restrict__ V, bf16* __restrict__ O) {
    __shared__ bf16 Ks[64 * 64];
    __shared__ bf16 Vt[64 * 64];
    __shared__ bf16 Ps[4][16 * 64];
    const int tid = threadIdx.x, lane = tid & 63, w = tid >> 6;
    const int lr = lane & 15, lg = lane >> 4;
    const int q0 = blockIdx.x * 64;
    const int bh = blockIdx.y;
    const int b = bh >> 4, h = bh & 15;
    const size_t base = ((size_t)b * S_) * D_ + (size_t)h * DK_;

    // Q fragments (A operand): row = lane&15, k = (lane>>4)*8 (+32 for second k-step)
    bf16x8 aq[2];
    {
        int qrow = q0 + w * 16 + lr;
        const bf16* qp = Q + base + (size_t)qrow * D_ + lg * 8;
        aq[0] = *reinterpret_cast<const bf16x8*>(qp);
        aq[1] = *reinterpret_cast<const bf16x8*>(qp + 32);
    }

    f32x4 acc_o[4] = {};
    float m_run[4] = {-1e30f, -1e30f, -1e30f, -1e30f};
    float l_run[4] = {0.f, 0.f, 0.f, 0.f};

    for (int j0 = 0; j0 <= q0; j0 += 64) {
        __syncthreads();
        // stage K [64][64] (swizzled) and V^T [dd][kv] (swizzled)
#pragma unroll
        for (int i = 0; i < 2; ++i) {
            int jj = (tid >> 3) + i * 32;
            int e0 = (tid & 7) * 8;
            bf16x8 kv = *reinterpret_cast<const bf16x8*>(&Kr[base + (size_t)(j0 + jj) * D_ + e0]);
            *reinterpret_cast<bf16x8*>(&Ks[jj * 64 + (e0 ^ ((jj & 7) << 3))]) = kv;
            bf16x8 vv = *reinterpret_cast<const bf16x8*>(&V[base + (size_t)(j0 + jj) * D_ + e0]);
#pragma unroll
            for (int q = 0; q < 8; ++q) {
                int e = e0 + q;
                Vt[e * 64 + (jj ^ ((e & 7) << 3))] = vv[q];
            }
        }
        __syncthreads();

        // scores: S = Q K^T ; B-frag col = kv j = lane&15, k = dk dim
        f32x4 sc[4];
#pragma unroll
        for (int nt = 0; nt < 4; ++nt) {
            int krow = nt * 16 + lr;
            int swz = (krow & 7) << 3;
            bf16x8 b0 = *reinterpret_cast<const bf16x8*>(&Ks[krow * 64 + ((lg * 8) ^ swz)]);
            bf16x8 b1 = *reinterpret_cast<const bf16x8*>(&Ks[krow * 64 + ((32 + lg * 8) ^ swz)]);
            f32x4 t = {};
            t = __builtin_amdgcn_mfma_f32_16x16x32_bf16(aq[0], b0, t, 0, 0, 0);
            t = __builtin_amdgcn_mfma_f32_16x16x32_bf16(aq[1], b1, t, 0, 0, 0);
            sc[nt] = t;
        }
        // scale + causal mask (only diagonal tile needs it)
#pragma unroll
        for (int nt = 0; nt < 4; ++nt)
#pragma unroll
            for (int r = 0; r < 4; ++r) {
                float s = sc[nt][r] * 0.125f;
                if (j0 == q0) {
                    int col = j0 + nt * 16 + lr;
                    int row = q0 + w * 16 + lg * 4 + r;
                    if (col > row) s = -1e30f;
                }
                sc[nt][r] = s;
            }
        // online softmax per q-row (row r lives in the 16-lane group sharing lane>>4)
#pragma unroll
        for (int r = 0; r < 4; ++r) {
            float mx = fmaxf(fmaxf(sc[0][r], sc[1][r]), fmaxf(sc[2][r], sc[3][r]));
            mx = fmaxf(mx, __shfl_xor(mx, 1, 64));
            mx = fmaxf(mx, __shfl_xor(mx, 2, 64));
            mx = fmaxf(mx, __shfl_xor(mx, 4, 64));
            mx = fmaxf(mx, __shfl_xor(mx, 8, 64));
            float mnew = fmaxf(m_run[r], mx);
            float corr = __expf(m_run[r] - mnew);
            float rs = 0.f;
#pragma unroll
            for (int nt = 0; nt < 4; ++nt) {
                float p = __expf(sc[nt][r] - mnew);
                sc[nt][r] = p;
                rs += p;
            }
            rs += __shfl_xor(rs, 1, 64);
            rs += __shfl_xor(rs, 2, 64);
            rs += __shfl_xor(rs, 4, 64);
            rs += __shfl_xor(rs, 8, 64);
            l_run[r] = l_run[r] * corr + rs;
            m_run[r] = mnew;
#pragma unroll
            for (int dt = 0; dt < 4; ++dt) acc_o[dt][r] *= corr;
        }
        // write P to wave-private LDS (swizzled) to re-layout for PV A operand
#pragma unroll
        for (int nt = 0; nt < 4; ++nt)
#pragma unroll
            for (int r = 0; r < 4; ++r) {
                int row = lg * 4 + r;
                int col = nt * 16 + lr;
                Ps[w][row * 64 + (col ^ ((row & 7) << 3))] = (bf16)sc[nt][r];
            }
        // PV: A = P (row = q = lane&15, k = kv), B = V (col = dd, k = kv)
        bf16x8 ap[2];
        {
            int row = lr;
            int swz = (row & 7) << 3;
            ap[0] = *reinterpret_cast<const bf16x8*>(&Ps[w][row * 64 + ((lg * 8) ^ swz)]);
            ap[1] = *reinterpret_cast<const bf16x8*>(&Ps[w][row * 64 + ((32 + lg * 8) ^ swz)]);
        }
#pragma unroll
        for (int dt = 0; dt < 4; ++dt) {
            int vrow = dt * 16 + lr;
            int swz = (vrow & 7) << 3;
            bf16x8 b0 = *reinterpret_cast<const bf16x8*>(&Vt[vrow * 64 + ((lg * 8) ^ swz)]);
            bf16x8 b1 = *reinterpret_cast<const bf16x8*>(&Vt[vrow * 64 + ((32 + lg * 8) ^ swz)]);
            acc_o[dt] = __builtin_amdgcn_mfma_f32_16x16x32_bf16(ap[0], b0, acc_o[dt], 0, 0, 0);
            acc_o[dt] = __builtin_amdgcn_mfma_f32_16x16x32_bf16(ap[1], b1, acc_o[dt], 0, 0, 0);
        }
    }
    // epilogue: normalize and store [n][D] bf16
#pragma unroll
    for (int r = 0; r < 4; ++r) {
        float inv = 1.0f / l_run[r];
        int row = q0 + w * 16 + lg * 4 + r;
#pragma unroll
        for (int dt = 0; dt < 4; ++dt) {
            O[base + (size_t)row * D_ + dt * 16 + lr] = (bf16)(acc_o[dt][r] * inv);
        }
    }
}

// ---------------- launcher ----------------
extern "C" void kernel_launch(void* const* d_in, const int* in_sizes, int n_in,
                              void* d_out, int out_size, void* d_ws, size_t ws_size,
                              hipStream_t stream) {
    const float* x  = (const float*)d_in[0];
    const int*   tp = (const int*)d_in[1];
    const float* wq = (const float*)d_in[2];
    const float* wk = (const float*)d_in[3];
    const float* wv = (const float*)d_in[4];
    const float* wo = (const float*)d_in[5];

    bf16* ws = (bf16*)d_ws;
    bf16* Xbf = ws;                                   // 8192*1024
    bf16* Wqb = Xbf + (size_t)NTOK * D_;
    bf16* Wkb = Wqb + (size_t)D_ * D_;
    bf16* Wvb = Wkb + (size_t)D_ * D_;
    bf16* Wob = Wvb + (size_t)D_ * D_;
    bf16* Qr  = Wob + (size_t)D_ * D_;
    bf16* Kb  = Qr + (size_t)NTOK * D_;
    bf16* Vb  = Kb + (size_t)NTOK * D_;
    bf16* AO  = Vb + (size_t)NTOK * D_;
    float2* tab = (float2*)(AO + (size_t)NTOK * D_); // NTOK*32 float2
    (void)ws_size; (void)in_sizes; (void)n_in; (void)out_size;

    // converts
    {
        int n8 = NTOK * D_ / 8;
        cvt_f32_bf16<<<(n8 + 255) / 256, 256, 0, stream>>>(x, Xbf, n8);
        int w8 = D_ * D_ / 8;
        cvt_f32_bf16<<<(w8 + 255) / 256, 256, 0, stream>>>(wq, Wqb, w8);
        cvt_f32_bf16<<<(w8 + 255) / 256, 256, 0, stream>>>(wk, Wkb, w8);
        cvt_f32_bf16<<<(w8 + 255) / 256, 256, 0, stream>>>(wv, Wvb, w8);
        cvt_f32_bf16<<<(w8 + 255) / 256, 256, 0, stream>>>(wo, Wob, w8);
    }
    // rope table
    rope_table<<<(NTOK * 32 + 255) / 256, 256, 0, stream>>>(tp, tab);

    dim3 ggrid(NTOK / 128, D_ / 128);
    gemm_bt<1><<<ggrid, 256, 0, stream>>>(Xbf, Wqb, Qr, tab);
    gemm_bt<1><<<ggrid, 256, 0, stream>>>(Xbf, Wkb, Kb, tab);
    gemm_bt<0><<<ggrid, 256, 0, stream>>>(Xbf, Wvb, Vb, nullptr);

    flash_attn<<<dim3(S_ / 64, B_ * H_), 256, 0, stream>>>(Qr, Kb, Vb, AO);

    gemm_bt<2><<<ggrid, 256, 0, stream>>>(AO, Wob, d_out, nullptr);
}

// Round 2
// 359.299 us; speedup vs baseline: 1.2281x; 1.2281x over previous
//
#include <hip/hip_runtime.h>
#include <hip/hip_bf16.h>
#include <cstdint>
#include <cstddef>

#define B_ 4
#define S_ 2048
#define D_ 1024
#define H_ 16
#define DK_ 64
#define NTOK (B_*S_)

typedef __bf16 bf16;
typedef __bf16 bf16x8 __attribute__((ext_vector_type(8)));
typedef short s16x4 __attribute__((ext_vector_type(4)));
typedef float f32x4 __attribute__((ext_vector_type(4)));

static __device__ __forceinline__ short f2bf_s(float f) {
    return __builtin_bit_cast(short, (__bf16)f);
}

static __device__ __forceinline__ f32x4 mfma16(s16x4 a, s16x4 b, f32x4 c) {
#if __has_builtin(__builtin_amdgcn_mfma_f32_16x16x16bf16_1k)
    return __builtin_amdgcn_mfma_f32_16x16x16bf16_1k(a, b, c, 0, 0, 0);
#else
    asm volatile("v_mfma_f32_16x16x16_bf16 %0, %1, %2, %0\n\ts_nop 7\n\ts_nop 7"
                 : "+v"(c) : "v"(a), "v"(b));
    return c;
#endif
}

// ---------------- fp32 -> bf16 convert (vectorized) ----------------
__global__ void cvt_f32_bf16(const float* __restrict__ src, bf16* __restrict__ dst, int n8) {
    int i = blockIdx.x * blockDim.x + threadIdx.x;
    if (i >= n8) return;
    const float4* s4 = reinterpret_cast<const float4*>(src) + (size_t)i * 2;
    float4 a = s4[0], b = s4[1];
    bf16x8 o;
    o[0] = (bf16)a.x; o[1] = (bf16)a.y; o[2] = (bf16)a.z; o[3] = (bf16)a.w;
    o[4] = (bf16)b.x; o[5] = (bf16)b.y; o[6] = (bf16)b.z; o[7] = (bf16)b.w;
    reinterpret_cast<bf16x8*>(dst)[i] = o;
}

// ---------------- RoPE cos/sin table: [NTOK][32] float2 ----------------
__global__ void rope_table(const int* __restrict__ pos, float2* __restrict__ tab) {
    int i = blockIdx.x * blockDim.x + threadIdx.x;
    if (i >= NTOK * 32) return;
    int n = i >> 5, p = i & 31;
    float pf = (float)pos[n];
    float freq = powf(10000.0f, -(float)p * (1.0f / 32.0f));
    float ang = pf * freq;
    float s, c;
    sincosf(ang, &s, &c);
    tab[i] = make_float2(c, s);
}

// ---------------- GEMM C = A @ Bw^T (unchanged m97-style 128x128) ----------------
template<int MODE>
__global__ __launch_bounds__(256)
void gemm_bt(const bf16* __restrict__ A, const bf16* __restrict__ Bw,
             void* __restrict__ Cp, const float2* __restrict__ tab) {
    constexpr int K = 1024, N = 1024;
    __shared__ bf16 As[128 * 32];
    __shared__ bf16 Bs[128 * 32];
    const int tid = threadIdx.x;
    const int lane = tid & 63;
    const int w = tid >> 6;
    const int wr = w >> 1, wc = w & 1;
    const int m0 = blockIdx.x * 128;
    const int n0 = blockIdx.y * 128;
    const int lr = lane & 15, lg = lane >> 4;

    f32x4 acc[4][4] = {};

    for (int kt = 0; kt < K / 32; ++kt) {
        __syncthreads();
#pragma unroll
        for (int i = 0; i < 2; ++i) {
            int eoff = (i * 256 + tid) * 8;
            int r = eoff >> 5, c = eoff & 31;
            __builtin_amdgcn_global_load_lds(
                (const __attribute__((address_space(1))) uint32_t*)(&A[(size_t)(m0 + r) * K + kt * 32 + c]),
                (__attribute__((address_space(3))) uint32_t*)(&As[eoff]), 16, 0, 0);
            __builtin_amdgcn_global_load_lds(
                (const __attribute__((address_space(1))) uint32_t*)(&Bw[(size_t)(n0 + r) * K + kt * 32 + c]),
                (__attribute__((address_space(3))) uint32_t*)(&Bs[eoff]), 16, 0, 0);
        }
        __syncthreads();
        bf16x8 af[4], bfr[4];
#pragma unroll
        for (int m = 0; m < 4; ++m)
            af[m] = *reinterpret_cast<const bf16x8*>(&As[(wr * 64 + m * 16 + lr) * 32 + lg * 8]);
#pragma unroll
        for (int n = 0; n < 4; ++n)
            bfr[n] = *reinterpret_cast<const bf16x8*>(&Bs[(wc * 64 + n * 16 + lr) * 32 + lg * 8]);
#pragma unroll
        for (int m = 0; m < 4; ++m)
#pragma unroll
            for (int n = 0; n < 4; ++n)
                acc[m][n] = __builtin_amdgcn_mfma_f32_16x16x32_bf16(af[m], bfr[n], acc[m][n], 0, 0, 0);
    }

#pragma unroll
    for (int mt = 0; mt < 4; ++mt) {
#pragma unroll
        for (int nt = 0; nt < 4; ++nt) {
#pragma unroll
            for (int r = 0; r < 4; ++r) {
                int row = m0 + wr * 64 + mt * 16 + lg * 4 + r;
                int col = n0 + wc * 64 + nt * 16 + lr;
                float v = acc[mt][nt][r];
                if (MODE == 2) {
                    ((float*)Cp)[(size_t)row * N + col] = v;
                } else if (MODE == 0) {
                    ((bf16*)Cp)[(size_t)row * N + col] = (bf16)v;
                } else {
                    float partner = __shfl_xor(v, 1, 64);
                    float2 cs = tab[(size_t)row * 32 + ((col >> 1) & 31)];
                    float o = (col & 1) ? fmaf(v, cs.x, partner * cs.y)
                                        : fmaf(v, cs.x, -partner * cs.y);
                    ((bf16*)Cp)[(size_t)row * N + col] = (bf16)o;
                }
            }
        }
    }
}

// ---------------- causal flash attention, swapped-QK^T ----------------
// grid (S/128, B*H), 256 threads = 4 waves, each wave owns 32 q-rows.
// KV tile = 64. Swapped QK: mfma(A=K, B=Q) -> lane holds full score row for q=lane&15.
// P feeds PV directly via mfma_16x16x16 A-frag layout (k = lg*4+j == C-layout row).
__global__ __launch_bounds__(256)
void flash_attn2(const bf16* __restrict__ Q, const bf16* __restrict__ Kr,
                 const bf16* __restrict__ V, bf16* __restrict__ O) {
    __shared__ bf16 Ks[64 * 64];
    __shared__ bf16 Vt[64 * 64];
    const int tid = threadIdx.x, lane = tid & 63, w = tid >> 6;
    const int lr = lane & 15, lg = lane >> 4;
    const int qt = (int)(gridDim.x - 1 - blockIdx.x);   // heavy-first dispatch
    const int q0 = qt * 128;
    const int bh = blockIdx.y;
    const int b = bh >> 4, h = bh & 15;
    const size_t base = ((size_t)b * S_) * D_ + (size_t)h * DK_;
    const float SCL2E = 0.125f * 1.44269504088896340736f;

    // Q fragments (B operand): col = lane&15 = q, k = lg*8 (+kk*32)
    bf16x8 aq[2][2];
#pragma unroll
    for (int qs = 0; qs < 2; ++qs) {
        int qrow = q0 + w * 32 + qs * 16 + lr;
        const bf16* qp = Q + base + (size_t)qrow * D_ + lg * 8;
        aq[qs][0] = *reinterpret_cast<const bf16x8*>(qp);
        aq[qs][1] = *reinterpret_cast<const bf16x8*>(qp + 32);
    }

    f32x4 acc[2][4] = {};
    float m_run[2] = {-1e30f, -1e30f};
    float l_run[2] = {0.f, 0.f};

    const int ntiles = 2 * qt + 2;
    const int qmaxw = q0 + w * 32 + 31;

    for (int t = 0; t < ntiles; ++t) {
        const int j0 = t * 64;
        __syncthreads();
        // stage K [kv][64] and V^T [dd][kv], both XOR-swizzled
#pragma unroll
        for (int i = 0; i < 2; ++i) {
            int jj = (tid >> 3) + i * 32;
            int e0 = (tid & 7) * 8;
            bf16x8 kv = *reinterpret_cast<const bf16x8*>(&Kr[base + (size_t)(j0 + jj) * D_ + e0]);
            *reinterpret_cast<bf16x8*>(&Ks[jj * 64 + (e0 ^ ((jj & 7) << 3))]) = kv;
            bf16x8 vv = *reinterpret_cast<const bf16x8*>(&V[base + (size_t)(j0 + jj) * D_ + e0]);
#pragma unroll
            for (int q = 0; q < 8; ++q) {
                int e = e0 + q;
                Vt[e * 64 + (jj ^ ((e & 7) << 3))] = vv[q];
            }
        }
        __syncthreads();
        if (j0 > qmaxw) continue;   // fully masked for this wave (barriers already passed)

        // S^T = K Q^T : A = K rows (row=lane&15=kv), B = Q (col=lane&15=q)
        f32x4 sc[2][4];
#pragma unroll
        for (int nt = 0; nt < 4; ++nt) {
            int krow = nt * 16 + lr;
            int swz = (krow & 7) << 3;
            bf16x8 a0 = *reinterpret_cast<const bf16x8*>(&Ks[krow * 64 + ((lg * 8) ^ swz)]);
            bf16x8 a1 = *reinterpret_cast<const bf16x8*>(&Ks[krow * 64 + ((32 + lg * 8) ^ swz)]);
#pragma unroll
            for (int qs = 0; qs < 2; ++qs) {
                f32x4 tv = {};
                tv = __builtin_amdgcn_mfma_f32_16x16x32_bf16(a0, aq[qs][0], tv, 0, 0, 0);
                tv = __builtin_amdgcn_mfma_f32_16x16x32_bf16(a1, aq[qs][1], tv, 0, 0, 0);
                sc[qs][nt] = tv;
            }
        }

        s16x4 ap[2][4];
#pragma unroll
        for (int qs = 0; qs < 2; ++qs) {
            const int qrow = q0 + w * 32 + qs * 16 + lr;  // this lane's q
            // scale (log2e folded) + causal mask
            if (j0 + 63 > q0 + w * 32 + qs * 16) {
#pragma unroll
                for (int nt = 0; nt < 4; ++nt)
#pragma unroll
                    for (int r = 0; r < 4; ++r) {
                        int kv = j0 + nt * 16 + lg * 4 + r;
                        float s = sc[qs][nt][r] * SCL2E;
                        sc[qs][nt][r] = (kv > qrow) ? -1e30f : s;
                    }
            } else {
#pragma unroll
                for (int nt = 0; nt < 4; ++nt)
#pragma unroll
                    for (int r = 0; r < 4; ++r)
                        sc[qs][nt][r] *= SCL2E;
            }
            // row max: 16 in-reg + 2 shfl (combine lg groups)
            float tmax = sc[qs][0][0];
#pragma unroll
            for (int nt = 0; nt < 4; ++nt)
#pragma unroll
                for (int r = 0; r < 4; ++r) tmax = fmaxf(tmax, sc[qs][nt][r]);
            tmax = fmaxf(tmax, __shfl_xor(tmax, 16, 64));
            tmax = fmaxf(tmax, __shfl_xor(tmax, 32, 64));
            float mnew = fmaxf(m_run[qs], tmax);
            float corr = exp2f(m_run[qs] - mnew);
            m_run[qs] = mnew;
            float rs = 0.f;
#pragma unroll
            for (int nt = 0; nt < 4; ++nt)
#pragma unroll
                for (int r = 0; r < 4; ++r) {
                    float p = exp2f(sc[qs][nt][r] - mnew);
                    rs += p;
                    ap[qs][nt][r] = f2bf_s(p);
                }
            rs += __shfl_xor(rs, 16, 64);
            rs += __shfl_xor(rs, 32, 64);
            l_run[qs] = l_run[qs] * corr + rs;
            // rescale acc: acc rows are q = lg*4+r; corr lives at lane lr=q
#pragma unroll
            for (int r = 0; r < 4; ++r) {
                float cr = __shfl(corr, (lane & 48) | (lg * 4 + r), 64);
#pragma unroll
                for (int dt = 0; dt < 4; ++dt) acc[qs][dt][r] *= cr;
            }
        }

        // PV: A = P (row=q, k=lg*4+j  == held values), B = V^T slices
#pragma unroll
        for (int dt = 0; dt < 4; ++dt) {
            int vrow = dt * 16 + lr;
            int vswz = (vrow & 7) << 3;
            s16x4 bv[4];
#pragma unroll
            for (int nt = 0; nt < 4; ++nt)
                bv[nt] = *reinterpret_cast<const s16x4*>(&Vt[vrow * 64 + ((nt * 16 + lg * 4) ^ vswz)]);
#pragma unroll
            for (int qs = 0; qs < 2; ++qs)
#pragma unroll
                for (int nt = 0; nt < 4; ++nt)
                    acc[qs][dt] = mfma16(ap[qs][nt], bv[nt], acc[qs][dt]);
        }
    }

    // epilogue: normalize (l lives at lane lr=q; acc rows q=lg*4+r) and store
#pragma unroll
    for (int qs = 0; qs < 2; ++qs) {
        float inv = 1.0f / l_run[qs];
#pragma unroll
        for (int r = 0; r < 4; ++r) {
            float invr = __shfl(inv, (lane & 48) | (lg * 4 + r), 64);
            int row = q0 + w * 32 + qs * 16 + lg * 4 + r;
#pragma unroll
            for (int dt = 0; dt < 4; ++dt)
                O[base + (size_t)row * D_ + dt * 16 + lr] = (bf16)(acc[qs][dt][r] * invr);
        }
    }
}

// ---------------- launcher ----------------
extern "C" void kernel_launch(void* const* d_in, const int* in_sizes, int n_in,
                              void* d_out, int out_size, void* d_ws, size_t ws_size,
                              hipStream_t stream) {
    const float* x  = (const float*)d_in[0];
    const int*   tp = (const int*)d_in[1];
    const float* wq = (const float*)d_in[2];
    const float* wk = (const float*)d_in[3];
    const float* wv = (const float*)d_in[4];
    const float* wo = (const float*)d_in[5];

    bf16* ws = (bf16*)d_ws;
    bf16* Xbf = ws;                                   // 8192*1024
    bf16* Wqb = Xbf + (size_t)NTOK * D_;
    bf16* Wkb = Wqb + (size_t)D_ * D_;
    bf16* Wvb = Wkb + (size_t)D_ * D_;
    bf16* Wob = Wvb + (size_t)D_ * D_;
    bf16* Qr  = Wob + (size_t)D_ * D_;
    bf16* Kb  = Qr + (size_t)NTOK * D_;
    bf16* Vb  = Kb + (size_t)NTOK * D_;
    bf16* AO  = Vb + (size_t)NTOK * D_;
    float2* tab = (float2*)(AO + (size_t)NTOK * D_); // NTOK*32 float2
    (void)ws_size; (void)in_sizes; (void)n_in; (void)out_size;

    {
        int n8 = NTOK * D_ / 8;
        cvt_f32_bf16<<<(n8 + 255) / 256, 256, 0, stream>>>(x, Xbf, n8);
        int w8 = D_ * D_ / 8;
        cvt_f32_bf16<<<(w8 + 255) / 256, 256, 0, stream>>>(wq, Wqb, w8);
        cvt_f32_bf16<<<(w8 + 255) / 256, 256, 0, stream>>>(wk, Wkb, w8);
        cvt_f32_bf16<<<(w8 + 255) / 256, 256, 0, stream>>>(wv, Wvb, w8);
        cvt_f32_bf16<<<(w8 + 255) / 256, 256, 0, stream>>>(wo, Wob, w8);
    }
    rope_table<<<(NTOK * 32 + 255) / 256, 256, 0, stream>>>(tp, tab);

    dim3 ggrid(NTOK / 128, D_ / 128);
    gemm_bt<1><<<ggrid, 256, 0, stream>>>(Xbf, Wqb, Qr, tab);
    gemm_bt<1><<<ggrid, 256, 0, stream>>>(Xbf, Wkb, Kb, tab);
    gemm_bt<0><<<ggrid, 256, 0, stream>>>(Xbf, Wvb, Vb, nullptr);

    flash_attn2<<<dim3(S_ / 128, B_ * H_), 256, 0, stream>>>(Qr, Kb, Vb, AO);

    gemm_bt<2><<<ggrid, 256, 0, stream>>>(AO, Wob, d_out, nullptr);
}

// Round 3
// 260.808 us; speedup vs baseline: 1.6918x; 1.3776x over previous
//
#include <hip/hip_runtime.h>
#include <hip/hip_bf16.h>
#include <cstdint>
#include <cstddef>

#define B_ 4
#define S_ 2048
#define D_ 1024
#define H_ 16
#define DK_ 64
#define NTOK (B_*S_)

typedef __bf16 bf16;
typedef __bf16 bf16x8 __attribute__((ext_vector_type(8)));
typedef short s16x4 __attribute__((ext_vector_type(4)));
typedef float f32x4 __attribute__((ext_vector_type(4)));

static __device__ __forceinline__ short f2bf_s(float f) {
    return __builtin_bit_cast(short, (__bf16)f);
}

static __device__ __forceinline__ f32x4 mfma16(s16x4 a, s16x4 b, f32x4 c) {
#if __has_builtin(__builtin_amdgcn_mfma_f32_16x16x16bf16_1k)
    return __builtin_amdgcn_mfma_f32_16x16x16bf16_1k(a, b, c, 0, 0, 0);
#else
    asm volatile("v_mfma_f32_16x16x16_bf16 %0, %1, %2, %0\n\ts_nop 7\n\ts_nop 7"
                 : "+v"(c) : "v"(a), "v"(b));
    return c;
#endif
}

// ---------------- fp32 -> bf16 convert (vectorized) ----------------
__global__ void cvt_f32_bf16(const float* __restrict__ src, bf16* __restrict__ dst, int n8) {
    int i = blockIdx.x * blockDim.x + threadIdx.x;
    if (i >= n8) return;
    const float4* s4 = reinterpret_cast<const float4*>(src) + (size_t)i * 2;
    float4 a = s4[0], b = s4[1];
    bf16x8 o;
    o[0] = (bf16)a.x; o[1] = (bf16)a.y; o[2] = (bf16)a.z; o[3] = (bf16)a.w;
    o[4] = (bf16)b.x; o[5] = (bf16)b.y; o[6] = (bf16)b.z; o[7] = (bf16)b.w;
    reinterpret_cast<bf16x8*>(dst)[i] = o;
}

// ---------------- RoPE cos/sin table: [NTOK][32] float2 ----------------
__global__ void rope_table(const int* __restrict__ pos, float2* __restrict__ tab) {
    int i = blockIdx.x * blockDim.x + threadIdx.x;
    if (i >= NTOK * 32) return;
    int n = i >> 5, p = i & 31;
    float pf = (float)pos[n];
    float freq = powf(10000.0f, -(float)p * (1.0f / 32.0f));
    float ang = pf * freq;
    float s, c;
    sincosf(ang, &s, &c);
    tab[i] = make_float2(c, s);
}

// ---------------- fused QKV GEMM: C = X @ W^T for W in {Wq,Wk,Wv} ----------------
// grid (64, 24): y selects (which, n0). RoPE fused for Q,K.
__global__ __launch_bounds__(256)
void gemm_qkv(const bf16* __restrict__ A, const bf16* __restrict__ Wq,
              const bf16* __restrict__ Wk, const bf16* __restrict__ Wv,
              bf16* __restrict__ Out, const float2* __restrict__ tab) {
    constexpr int K = 1024, N = 1024;
    __shared__ bf16 As[128 * 32];
    __shared__ bf16 Bs[128 * 32];
    const int yb = blockIdx.y;
    const int which = yb >> 3;              // 0=Q,1=K,2=V
    const int n0 = (yb & 7) * 128;
    const bf16* Bw = which == 0 ? Wq : (which == 1 ? Wk : Wv);
    bf16* Cp = Out + (size_t)which * NTOK * D_;
    const bool do_rope = which < 2;

    const int tid = threadIdx.x;
    const int lane = tid & 63;
    const int w = tid >> 6;
    const int wr = w >> 1, wc = w & 1;
    const int m0 = blockIdx.x * 128;
    const int lr = lane & 15, lg = lane >> 4;

    f32x4 acc[4][4] = {};

    for (int kt = 0; kt < K / 32; ++kt) {
        __syncthreads();
#pragma unroll
        for (int i = 0; i < 2; ++i) {
            int eoff = (i * 256 + tid) * 8;
            int r = eoff >> 5, c = eoff & 31;
            __builtin_amdgcn_global_load_lds(
                (const __attribute__((address_space(1))) uint32_t*)(&A[(size_t)(m0 + r) * K + kt * 32 + c]),
                (__attribute__((address_space(3))) uint32_t*)(&As[eoff]), 16, 0, 0);
            __builtin_amdgcn_global_load_lds(
                (const __attribute__((address_space(1))) uint32_t*)(&Bw[(size_t)(n0 + r) * K + kt * 32 + c]),
                (__attribute__((address_space(3))) uint32_t*)(&Bs[eoff]), 16, 0, 0);
        }
        __syncthreads();
        bf16x8 af[4], bfr[4];
#pragma unroll
        for (int m = 0; m < 4; ++m)
            af[m] = *reinterpret_cast<const bf16x8*>(&As[(wr * 64 + m * 16 + lr) * 32 + lg * 8]);
#pragma unroll
        for (int n = 0; n < 4; ++n)
            bfr[n] = *reinterpret_cast<const bf16x8*>(&Bs[(wc * 64 + n * 16 + lr) * 32 + lg * 8]);
#pragma unroll
        for (int m = 0; m < 4; ++m)
#pragma unroll
            for (int n = 0; n < 4; ++n)
                acc[m][n] = __builtin_amdgcn_mfma_f32_16x16x32_bf16(af[m], bfr[n], acc[m][n], 0, 0, 0);
    }

#pragma unroll
    for (int mt = 0; mt < 4; ++mt) {
#pragma unroll
        for (int nt = 0; nt < 4; ++nt) {
#pragma unroll
            for (int r = 0; r < 4; ++r) {
                int row = m0 + wr * 64 + mt * 16 + lg * 4 + r;
                int col = n0 + wc * 64 + nt * 16 + lr;
                float v = acc[mt][nt][r];
                if (do_rope) {
                    float partner = __shfl_xor(v, 1, 64);
                    float2 cs = tab[(size_t)row * 32 + ((col >> 1) & 31)];
                    float o = (col & 1) ? fmaf(v, cs.x, partner * cs.y)
                                        : fmaf(v, cs.x, -partner * cs.y);
                    Cp[(size_t)row * N + col] = (bf16)o;
                } else {
                    Cp[(size_t)row * N + col] = (bf16)v;
                }
            }
        }
    }
}

// ---------------- output GEMM: fp32 out ----------------
__global__ __launch_bounds__(256)
void gemm_out(const bf16* __restrict__ A, const bf16* __restrict__ Bw,
              float* __restrict__ Cp) {
    constexpr int K = 1024, N = 1024;
    __shared__ bf16 As[128 * 32];
    __shared__ bf16 Bs[128 * 32];
    const int tid = threadIdx.x;
    const int lane = tid & 63;
    const int w = tid >> 6;
    const int wr = w >> 1, wc = w & 1;
    const int m0 = blockIdx.x * 128;
    const int n0 = blockIdx.y * 128;
    const int lr = lane & 15, lg = lane >> 4;

    f32x4 acc[4][4] = {};

    for (int kt = 0; kt < K / 32; ++kt) {
        __syncthreads();
#pragma unroll
        for (int i = 0; i < 2; ++i) {
            int eoff = (i * 256 + tid) * 8;
            int r = eoff >> 5, c = eoff & 31;
            __builtin_amdgcn_global_load_lds(
                (const __attribute__((address_space(1))) uint32_t*)(&A[(size_t)(m0 + r) * K + kt * 32 + c]),
                (__attribute__((address_space(3))) uint32_t*)(&As[eoff]), 16, 0, 0);
            __builtin_amdgcn_global_load_lds(
                (const __attribute__((address_space(1))) uint32_t*)(&Bw[(size_t)(n0 + r) * K + kt * 32 + c]),
                (__attribute__((address_space(3))) uint32_t*)(&Bs[eoff]), 16, 0, 0);
        }
        __syncthreads();
        bf16x8 af[4], bfr[4];
#pragma unroll
        for (int m = 0; m < 4; ++m)
            af[m] = *reinterpret_cast<const bf16x8*>(&As[(wr * 64 + m * 16 + lr) * 32 + lg * 8]);
#pragma unroll
        for (int n = 0; n < 4; ++n)
            bfr[n] = *reinterpret_cast<const bf16x8*>(&Bs[(wc * 64 + n * 16 + lr) * 32 + lg * 8]);
#pragma unroll
        for (int m = 0; m < 4; ++m)
#pragma unroll
            for (int n = 0; n < 4; ++n)
                acc[m][n] = __builtin_amdgcn_mfma_f32_16x16x32_bf16(af[m], bfr[n], acc[m][n], 0, 0, 0);
    }

#pragma unroll
    for (int mt = 0; mt < 4; ++mt)
#pragma unroll
        for (int nt = 0; nt < 4; ++nt)
#pragma unroll
            for (int r = 0; r < 4; ++r) {
                int row = m0 + wr * 64 + mt * 16 + lg * 4 + r;
                int col = n0 + wc * 64 + nt * 16 + lr;
                Cp[(size_t)row * N + col] = acc[mt][nt][r];
            }
}

// ---------------- causal flash attention, paired strips + async pipeline ----------------
// grid (8, 64), 256 threads = 4 waves. Block handles strips qtA=bx, qtB=15-bx
// (constant 36 compute-tile-units per block -> perfect balance, 512 co-resident blocks).
// KV staged via regs (T14): prefetch tile t+1 during compute of t; LDS double-buffered;
// ONE barrier per tile.
__global__ __launch_bounds__(256, 2)
void flash_attn3(const bf16* __restrict__ Q, const bf16* __restrict__ Kr,
                 const bf16* __restrict__ V, bf16* __restrict__ O) {
    __shared__ bf16 Ks[2][64 * 64];
    __shared__ bf16 Vt[2][64 * 64];
    const int tid = threadIdx.x, lane = tid & 63, w = tid >> 6;
    const int lr = lane & 15, lg = lane >> 4;
    const int qtA = blockIdx.x;            // 0..7
    const int qtB = 15 - qtA;              // 15..8
    const int q0[2] = { qtA * 128, qtB * 128 };
    const int ntS[2] = { 2 * qtA + 2, 2 * qtB + 2 };
    const int NT = ntS[1];
    const int bh = blockIdx.y;
    const int b = bh >> 4, h = bh & 15;
    const size_t base = ((size_t)b * S_) * D_ + (size_t)h * DK_;
    const float SCL2E = 0.125f * 1.44269504088896340736f;

    // Q fragments (B operand of swapped QK): col=lane&15=q, k=lg*8 (+32)
    bf16x8 aq[2][2][2];
#pragma unroll
    for (int si = 0; si < 2; ++si)
#pragma unroll
        for (int qs = 0; qs < 2; ++qs) {
            int qrow = q0[si] + w * 32 + qs * 16 + lr;
            const bf16* qp = Q + base + (size_t)qrow * D_ + lg * 8;
            aq[si][qs][0] = *reinterpret_cast<const bf16x8*>(qp);
            aq[si][qs][1] = *reinterpret_cast<const bf16x8*>(qp + 32);
        }

    f32x4 acc[2][2][4] = {};
    float m_run[2][2] = {{-1e30f, -1e30f}, {-1e30f, -1e30f}};
    float l_run[2][2] = {{0.f, 0.f}, {0.f, 0.f}};

    // staging: thread covers K/V rows sjj, sjj+32 at dd [se0, se0+8)
    const int sjj = tid >> 3;              // 0..31
    const int se0 = (tid & 7) * 8;
    bf16x8 kreg[2], vreg[2];
#pragma unroll
    for (int i = 0; i < 2; ++i) {
        int row = sjj + i * 32;
        kreg[i] = *reinterpret_cast<const bf16x8*>(&Kr[base + (size_t)row * D_ + se0]);
        vreg[i] = *reinterpret_cast<const bf16x8*>(&V [base + (size_t)row * D_ + se0]);
    }

    for (int t = 0; t < NT; ++t) {
        const int j0 = t * 64;
        bf16* KsB = Ks[t & 1];
        bf16* VtB = Vt[t & 1];
        // write staged regs -> LDS (K swizzled rows; V transposed+swizzled)
#pragma unroll
        for (int i = 0; i < 2; ++i) {
            int jj = sjj + i * 32;
            *reinterpret_cast<bf16x8*>(&KsB[jj * 64 + (se0 ^ ((jj & 7) << 3))]) = kreg[i];
#pragma unroll
            for (int q = 0; q < 8; ++q) {
                int e = se0 + q;
                VtB[e * 64 + (jj ^ ((e & 7) << 3))] = vreg[i][q];
            }
        }
        // prefetch tile t+1 (HBM latency hides under this tile's compute)
        if (t + 1 < NT) {
#pragma unroll
            for (int i = 0; i < 2; ++i) {
                int row = (t + 1) * 64 + sjj + i * 32;
                kreg[i] = *reinterpret_cast<const bf16x8*>(&Kr[base + (size_t)row * D_ + se0]);
                vreg[i] = *reinterpret_cast<const bf16x8*>(&V [base + (size_t)row * D_ + se0]);
            }
        }
        __syncthreads();

#pragma unroll
        for (int si = 0; si < 2; ++si) {
            if (t >= ntS[si]) continue;                  // strip A finished (block-uniform)
            const int qmaxw = q0[si] + w * 32 + 31;
            if (j0 > qmaxw) continue;                    // fully masked for this wave

            // S^T = K Q^T
            f32x4 sc[2][4];
            __builtin_amdgcn_s_setprio(1);
#pragma unroll
            for (int nt = 0; nt < 4; ++nt) {
                int krow = nt * 16 + lr;
                int swz = (krow & 7) << 3;
                bf16x8 a0 = *reinterpret_cast<const bf16x8*>(&KsB[krow * 64 + ((lg * 8) ^ swz)]);
                bf16x8 a1 = *reinterpret_cast<const bf16x8*>(&KsB[krow * 64 + ((32 + lg * 8) ^ swz)]);
#pragma unroll
                for (int qs = 0; qs < 2; ++qs) {
                    f32x4 tv = {};
                    tv = __builtin_amdgcn_mfma_f32_16x16x32_bf16(a0, aq[si][qs][0], tv, 0, 0, 0);
                    tv = __builtin_amdgcn_mfma_f32_16x16x32_bf16(a1, aq[si][qs][1], tv, 0, 0, 0);
                    sc[qs][nt] = tv;
                }
            }
            __builtin_amdgcn_s_setprio(0);

            s16x4 ap[2][4];
#pragma unroll
            for (int qs = 0; qs < 2; ++qs) {
                const int qrow = q0[si] + w * 32 + qs * 16 + lr;
                if (j0 + 63 > q0[si] + w * 32 + qs * 16) {
#pragma unroll
                    for (int nt = 0; nt < 4; ++nt)
#pragma unroll
                        for (int r = 0; r < 4; ++r) {
                            int kv = j0 + nt * 16 + lg * 4 + r;
                            float s = sc[qs][nt][r] * SCL2E;
                            sc[qs][nt][r] = (kv > qrow) ? -1e30f : s;
                        }
                } else {
#pragma unroll
                    for (int nt = 0; nt < 4; ++nt)
#pragma unroll
                        for (int r = 0; r < 4; ++r)
                            sc[qs][nt][r] *= SCL2E;
                }
                // row max (row = q = lane&15): 15 in-reg + 2 shfl
                float tmax = sc[qs][0][0];
#pragma unroll
                for (int nt = 0; nt < 4; ++nt)
#pragma unroll
                    for (int r = 0; r < 4; ++r) tmax = fmaxf(tmax, sc[qs][nt][r]);
                tmax = fmaxf(tmax, __shfl_xor(tmax, 16, 64));
                tmax = fmaxf(tmax, __shfl_xor(tmax, 32, 64));
                // T13 defer-max: only rescale when max grew past threshold (exp2 domain)
                float mold = m_run[si][qs];
                if (!__all(tmax - mold <= 8.0f)) {
                    float mnew = fmaxf(mold, tmax);
                    float corr = exp2f(mold - mnew);
                    m_run[si][qs] = mnew;
                    l_run[si][qs] *= corr;
#pragma unroll
                    for (int r = 0; r < 4; ++r) {
                        float cr = __shfl(corr, (lane & 48) | (lg * 4 + r), 64);
#pragma unroll
                        for (int dt = 0; dt < 4; ++dt) acc[si][qs][dt][r] *= cr;
                    }
                }
                float mnow = m_run[si][qs];
                float rs = 0.f;
#pragma unroll
                for (int nt = 0; nt < 4; ++nt)
#pragma unroll
                    for (int r = 0; r < 4; ++r) {
                        float p = exp2f(sc[qs][nt][r] - mnow);
                        rs += p;
                        ap[qs][nt][r] = f2bf_s(p);
                    }
                rs += __shfl_xor(rs, 16, 64);
                rs += __shfl_xor(rs, 32, 64);
                l_run[si][qs] += rs;
            }

            // PV: A = P (in-register), B = V^T slices
            __builtin_amdgcn_s_setprio(1);
#pragma unroll
            for (int dt = 0; dt < 4; ++dt) {
                int vrow = dt * 16 + lr;
                int vswz = (vrow & 7) << 3;
                s16x4 bv[4];
#pragma unroll
                for (int nt = 0; nt < 4; ++nt)
                    bv[nt] = *reinterpret_cast<const s16x4*>(&VtB[vrow * 64 + ((nt * 16 + lg * 4) ^ vswz)]);
#pragma unroll
                for (int qs = 0; qs < 2; ++qs)
#pragma unroll
                    for (int nt = 0; nt < 4; ++nt)
                        acc[si][qs][dt] = mfma16(ap[qs][nt], bv[nt], acc[si][qs][dt]);
            }
            __builtin_amdgcn_s_setprio(0);
        }
    }

    // epilogue
#pragma unroll
    for (int si = 0; si < 2; ++si)
#pragma unroll
        for (int qs = 0; qs < 2; ++qs) {
            float inv = 1.0f / l_run[si][qs];
#pragma unroll
            for (int r = 0; r < 4; ++r) {
                float invr = __shfl(inv, (lane & 48) | (lg * 4 + r), 64);
                int row = q0[si] + w * 32 + qs * 16 + lg * 4 + r;
#pragma unroll
                for (int dt = 0; dt < 4; ++dt)
                    O[base + (size_t)row * D_ + dt * 16 + lr] = (bf16)(acc[si][qs][dt][r] * invr);
            }
        }
}

// ---------------- launcher ----------------
extern "C" void kernel_launch(void* const* d_in, const int* in_sizes, int n_in,
                              void* d_out, int out_size, void* d_ws, size_t ws_size,
                              hipStream_t stream) {
    const float* x  = (const float*)d_in[0];
    const int*   tp = (const int*)d_in[1];
    const float* wq = (const float*)d_in[2];
    const float* wk = (const float*)d_in[3];
    const float* wv = (const float*)d_in[4];
    const float* wo = (const float*)d_in[5];

    bf16* ws = (bf16*)d_ws;
    bf16* Xbf = ws;                                   // 8192*1024
    bf16* Wqb = Xbf + (size_t)NTOK * D_;
    bf16* Wkb = Wqb + (size_t)D_ * D_;
    bf16* Wvb = Wkb + (size_t)D_ * D_;
    bf16* Wob = Wvb + (size_t)D_ * D_;
    bf16* Qr  = Wob + (size_t)D_ * D_;                // Q,K,V contiguous
    bf16* Kb  = Qr + (size_t)NTOK * D_;
    bf16* Vb  = Kb + (size_t)NTOK * D_;
    bf16* AO  = Vb + (size_t)NTOK * D_;
    float2* tab = (float2*)(AO + (size_t)NTOK * D_); // NTOK*32 float2
    (void)ws_size; (void)in_sizes; (void)n_in; (void)out_size;

    {
        int n8 = NTOK * D_ / 8;
        cvt_f32_bf16<<<(n8 + 255) / 256, 256, 0, stream>>>(x, Xbf, n8);
        int w8 = D_ * D_ / 8;
        cvt_f32_bf16<<<(w8 + 255) / 256, 256, 0, stream>>>(wq, Wqb, w8);
        cvt_f32_bf16<<<(w8 + 255) / 256, 256, 0, stream>>>(wk, Wkb, w8);
        cvt_f32_bf16<<<(w8 + 255) / 256, 256, 0, stream>>>(wv, Wvb, w8);
        cvt_f32_bf16<<<(w8 + 255) / 256, 256, 0, stream>>>(wo, Wob, w8);
    }
    rope_table<<<(NTOK * 32 + 255) / 256, 256, 0, stream>>>(tp, tab);

    gemm_qkv<<<dim3(NTOK / 128, 24), 256, 0, stream>>>(Xbf, Wqb, Wkb, Wvb, Qr, tab);

    flash_attn3<<<dim3(8, B_ * H_), 256, 0, stream>>>(Qr, Kb, Vb, AO);

    gemm_out<<<dim3(NTOK / 128, D_ / 128), 256, 0, stream>>>(AO, Wob, (float*)d_out);
}

// Round 5
// 237.779 us; speedup vs baseline: 1.8557x; 1.0969x over previous
//
#include <hip/hip_runtime.h>
#include <hip/hip_bf16.h>
#include <cstdint>
#include <cstddef>

#define B_ 4
#define S_ 2048
#define D_ 1024
#define H_ 16
#define DK_ 64
#define NTOK (B_*S_)

typedef __bf16 bf16;
typedef __bf16 bf16x8 __attribute__((ext_vector_type(8)));
typedef short s16x4 __attribute__((ext_vector_type(4)));
typedef float f32x4 __attribute__((ext_vector_type(4)));

static __device__ __forceinline__ short f2bf_s(float f) {
    return __builtin_bit_cast(short, (__bf16)f);
}

static __device__ __forceinline__ f32x4 mfma16(s16x4 a, s16x4 b, f32x4 c) {
#if __has_builtin(__builtin_amdgcn_mfma_f32_16x16x16bf16_1k)
    return __builtin_amdgcn_mfma_f32_16x16x16bf16_1k(a, b, c, 0, 0, 0);
#else
    asm volatile("v_mfma_f32_16x16x16_bf16 %0, %1, %2, %0\n\ts_nop 7\n\ts_nop 7"
                 : "+v"(c) : "v"(a), "v"(b));
    return c;
#endif
}

// ---------------- fused fp32 -> bf16 convert: [X | Wq | Wk | Wv | Wo] ----------------
__global__ void cvt_all(const float* __restrict__ x, const float* __restrict__ wq,
                        const float* __restrict__ wk, const float* __restrict__ wv,
                        const float* __restrict__ wo, bf16* __restrict__ dst) {
    const int NX8 = NTOK * D_ / 8;
    const int W8 = D_ * D_ / 8;          // 131072 = 2^17
    int i = blockIdx.x * blockDim.x + threadIdx.x;
    if (i >= NX8 + 4 * W8) return;
    const float* src; int j;
    if (i < NX8) { src = x; j = i; }
    else {
        int k = i - NX8;
        int w = k >> 17;
        j = k & (W8 - 1);
        src = w == 0 ? wq : (w == 1 ? wk : (w == 2 ? wv : wo));
    }
    const float4* s4 = reinterpret_cast<const float4*>(src) + (size_t)j * 2;
    float4 a = s4[0], b = s4[1];
    bf16x8 o;
    o[0] = (bf16)a.x; o[1] = (bf16)a.y; o[2] = (bf16)a.z; o[3] = (bf16)a.w;
    o[4] = (bf16)b.x; o[5] = (bf16)b.y; o[6] = (bf16)b.z; o[7] = (bf16)b.w;
    reinterpret_cast<bf16x8*>(dst)[i] = o;
}

// ---------------- RoPE cos/sin table: [NTOK][32] float2 ----------------
__global__ void rope_table(const int* __restrict__ pos, float2* __restrict__ tab) {
    int i = blockIdx.x * blockDim.x + threadIdx.x;
    if (i >= NTOK * 32) return;
    int n = i >> 5, p = i & 31;
    float pf = (float)pos[n];
    float freq = powf(10000.0f, -(float)p * (1.0f / 32.0f));
    float ang = pf * freq;
    float s, c;
    sincosf(ang, &s, &c);
    tab[i] = make_float2(c, s);
}

// ---------------- fused QKV GEMM: C = X @ W^T for W in {Wq,Wk,Wv} ----------------
// Q gets RoPE + softmax scale (0.125*log2e) folded in; K gets RoPE only.
__global__ __launch_bounds__(256)
void gemm_qkv(const bf16* __restrict__ A, const bf16* __restrict__ Wq,
              const bf16* __restrict__ Wk, const bf16* __restrict__ Wv,
              bf16* __restrict__ Out, const float2* __restrict__ tab) {
    constexpr int K = 1024, N = 1024;
    const float SCL2E = 0.125f * 1.44269504088896340736f;
    __shared__ bf16 As[128 * 32];
    __shared__ bf16 Bs[128 * 32];
    const int yb = blockIdx.y;
    const int which = yb >> 3;              // 0=Q,1=K,2=V
    const int n0 = (yb & 7) * 128;
    const bf16* Bw = which == 0 ? Wq : (which == 1 ? Wk : Wv);
    bf16* Cp = Out + (size_t)which * NTOK * D_;
    const bool do_rope = which < 2;

    const int tid = threadIdx.x;
    const int lane = tid & 63;
    const int w = tid >> 6;
    const int wr = w >> 1, wc = w & 1;
    const int m0 = blockIdx.x * 128;
    const int lr = lane & 15, lg = lane >> 4;

    f32x4 acc[4][4] = {};

    for (int kt = 0; kt < K / 32; ++kt) {
        __syncthreads();
#pragma unroll
        for (int i = 0; i < 2; ++i) {
            int eoff = (i * 256 + tid) * 8;
            int r = eoff >> 5, c = eoff & 31;
            __builtin_amdgcn_global_load_lds(
                (const __attribute__((address_space(1))) uint32_t*)(&A[(size_t)(m0 + r) * K + kt * 32 + c]),
                (__attribute__((address_space(3))) uint32_t*)(&As[eoff]), 16, 0, 0);
            __builtin_amdgcn_global_load_lds(
                (const __attribute__((address_space(1))) uint32_t*)(&Bw[(size_t)(n0 + r) * K + kt * 32 + c]),
                (__attribute__((address_space(3))) uint32_t*)(&Bs[eoff]), 16, 0, 0);
        }
        __syncthreads();
        bf16x8 af[4], bfr[4];
#pragma unroll
        for (int m = 0; m < 4; ++m)
            af[m] = *reinterpret_cast<const bf16x8*>(&As[(wr * 64 + m * 16 + lr) * 32 + lg * 8]);
#pragma unroll
        for (int n = 0; n < 4; ++n)
            bfr[n] = *reinterpret_cast<const bf16x8*>(&Bs[(wc * 64 + n * 16 + lr) * 32 + lg * 8]);
#pragma unroll
        for (int m = 0; m < 4; ++m)
#pragma unroll
            for (int n = 0; n < 4; ++n)
                acc[m][n] = __builtin_amdgcn_mfma_f32_16x16x32_bf16(af[m], bfr[n], acc[m][n], 0, 0, 0);
    }

#pragma unroll
    for (int mt = 0; mt < 4; ++mt) {
#pragma unroll
        for (int nt = 0; nt < 4; ++nt) {
#pragma unroll
            for (int r = 0; r < 4; ++r) {
                int row = m0 + wr * 64 + mt * 16 + lg * 4 + r;
                int col = n0 + wc * 64 + nt * 16 + lr;
                float v = acc[mt][nt][r];
                if (do_rope) {
                    float partner = __shfl_xor(v, 1, 64);
                    float2 cs = tab[(size_t)row * 32 + ((col >> 1) & 31)];
                    float o = (col & 1) ? fmaf(v, cs.x, partner * cs.y)
                                        : fmaf(v, cs.x, -partner * cs.y);
                    if (which == 0) o *= SCL2E;
                    Cp[(size_t)row * N + col] = (bf16)o;
                } else {
                    Cp[(size_t)row * N + col] = (bf16)v;
                }
            }
        }
    }
}

// ---------------- output GEMM: fp32 out ----------------
__global__ __launch_bounds__(256)
void gemm_out(const bf16* __restrict__ A, const bf16* __restrict__ Bw,
              float* __restrict__ Cp) {
    constexpr int K = 1024, N = 1024;
    __shared__ bf16 As[128 * 32];
    __shared__ bf16 Bs[128 * 32];
    const int tid = threadIdx.x;
    const int lane = tid & 63;
    const int w = tid >> 6;
    const int wr = w >> 1, wc = w & 1;
    const int m0 = blockIdx.x * 128;
    const int n0 = blockIdx.y * 128;
    const int lr = lane & 15, lg = lane >> 4;

    f32x4 acc[4][4] = {};

    for (int kt = 0; kt < K / 32; ++kt) {
        __syncthreads();
#pragma unroll
        for (int i = 0; i < 2; ++i) {
            int eoff = (i * 256 + tid) * 8;
            int r = eoff >> 5, c = eoff & 31;
            __builtin_amdgcn_global_load_lds(
                (const __attribute__((address_space(1))) uint32_t*)(&A[(size_t)(m0 + r) * K + kt * 32 + c]),
                (__attribute__((address_space(3))) uint32_t*)(&As[eoff]), 16, 0, 0);
            __builtin_amdgcn_global_load_lds(
                (const __attribute__((address_space(1))) uint32_t*)(&Bw[(size_t)(n0 + r) * K + kt * 32 + c]),
                (__attribute__((address_space(3))) uint32_t*)(&Bs[eoff]), 16, 0, 0);
        }
        __syncthreads();
        bf16x8 af[4], bfr[4];
#pragma unroll
        for (int m = 0; m < 4; ++m)
            af[m] = *reinterpret_cast<const bf16x8*>(&As[(wr * 64 + m * 16 + lr) * 32 + lg * 8]);
#pragma unroll
        for (int n = 0; n < 4; ++n)
            bfr[n] = *reinterpret_cast<const bf16x8*>(&Bs[(wc * 64 + n * 16 + lr) * 32 + lg * 8]);
#pragma unroll
        for (int m = 0; m < 4; ++m)
#pragma unroll
            for (int n = 0; n < 4; ++n)
                acc[m][n] = __builtin_amdgcn_mfma_f32_16x16x32_bf16(af[m], bfr[n], acc[m][n], 0, 0, 0);
    }

#pragma unroll
    for (int mt = 0; mt < 4; ++mt)
#pragma unroll
        for (int nt = 0; nt < 4; ++nt)
#pragma unroll
            for (int r = 0; r < 4; ++r) {
                int row = m0 + wr * 64 + mt * 16 + lg * 4 + r;
                int col = n0 + wc * 64 + nt * 16 + lr;
                Cp[(size_t)row * N + col] = acc[mt][nt][r];
            }
}

// ---------------- causal flash attention ----------------
// grid (8, 64), 256 threads = 4 waves; strips qtA=bx, qtB=15-bx (perfect balance).
// K LDS: row-major [kv][64], XOR swz (kv&7)<<3 (b128 writes/reads at BW floor).
// V LDS: transposed [dd][64kv], swz ((dd&7)^(dd>>3))&7 <<3:
//   writes: dd>>3 = tid&7 varies per lane -> banks fully spread (2-way, free);
//   reads (dd=dt*16+lr): lr0^lr3/lr1/lr2 spread -> 4-way b64 = BW floor.
__global__ __launch_bounds__(256, 2)
void flash_attn5(const bf16* __restrict__ Q, const bf16* __restrict__ Kr,
                 const bf16* __restrict__ V, bf16* __restrict__ O) {
    __shared__ bf16 Ks[2][64 * 64];
    __shared__ bf16 Vt[2][64 * 64];
    const int tid = threadIdx.x, lane = tid & 63, w = tid >> 6;
    const int lr = lane & 15, lg = lane >> 4;
    const int qtA = blockIdx.x;
    const int qtB = 15 - qtA;
    const int q0[2] = { qtA * 128, qtB * 128 };
    const int ntS[2] = { 2 * qtA + 2, 2 * qtB + 2 };
    const int NT = ntS[1];
    const int bh = blockIdx.y;
    const int b = bh >> 4, h = bh & 15;
    const size_t base = ((size_t)b * S_) * D_ + (size_t)h * DK_;

    // Q fragments (B operand of swapped QK): col=lane&15=q, k=lg*8 (+32)
    bf16x8 aq[2][2][2];
#pragma unroll
    for (int si = 0; si < 2; ++si)
#pragma unroll
        for (int qs = 0; qs < 2; ++qs) {
            int qrow = q0[si] + w * 32 + qs * 16 + lr;
            const bf16* qp = Q + base + (size_t)qrow * D_ + lg * 8;
            aq[si][qs][0] = *reinterpret_cast<const bf16x8*>(qp);
            aq[si][qs][1] = *reinterpret_cast<const bf16x8*>(qp + 32);
        }

    f32x4 acc[2][2][4] = {};
    float m_run[2][2] = {{-1e30f, -1e30f}, {-1e30f, -1e30f}};
    float l_run[2][2] = {{0.f, 0.f}, {0.f, 0.f}};

    // staging: thread covers K/V rows sjj, sjj+32 at dd [se0, se0+8)
    const int sjj = tid >> 3;
    const int se0 = (tid & 7) * 8;
    const int vx = tid & 7;                // = (se0+q)>>3 for q<8
    bf16x8 kreg[2], vreg[2];
#pragma unroll
    for (int i = 0; i < 2; ++i) {
        int row = sjj + i * 32;
        kreg[i] = *reinterpret_cast<const bf16x8*>(&Kr[base + (size_t)row * D_ + se0]);
        vreg[i] = *reinterpret_cast<const bf16x8*>(&V [base + (size_t)row * D_ + se0]);
    }

    for (int t = 0; t < NT; ++t) {
        const int j0 = t * 64;
        bf16* KsB = Ks[t & 1];
        bf16* VtB = Vt[t & 1];
#pragma unroll
        for (int i = 0; i < 2; ++i) {
            int jj = sjj + i * 32;
            *reinterpret_cast<bf16x8*>(&KsB[jj * 64 + (se0 ^ ((jj & 7) << 3))]) = kreg[i];
#pragma unroll
            for (int q = 0; q < 8; ++q) {
                int dd = se0 + q;
                int vswz = ((q ^ vx) & 7) << 3;     // ((dd&7)^(dd>>3))&7 << 3
                VtB[dd * 64 + (jj ^ vswz)] = vreg[i][q];
            }
        }
        if (t + 1 < NT) {
#pragma unroll
            for (int i = 0; i < 2; ++i) {
                int row = (t + 1) * 64 + sjj + i * 32;
                kreg[i] = *reinterpret_cast<const bf16x8*>(&Kr[base + (size_t)row * D_ + se0]);
                vreg[i] = *reinterpret_cast<const bf16x8*>(&V [base + (size_t)row * D_ + se0]);
            }
        }
        __syncthreads();

#pragma unroll
        for (int si = 0; si < 2; ++si) {
            if (t >= ntS[si]) continue;
            const int qmaxw = q0[si] + w * 32 + 31;
            if (j0 > qmaxw) continue;

            // S^T = K Q^T (Q pre-scaled by 0.125*log2e)
            f32x4 sc[2][4];
            __builtin_amdgcn_s_setprio(1);
#pragma unroll
            for (int nt = 0; nt < 4; ++nt) {
                int krow = nt * 16 + lr;
                int swz = (krow & 7) << 3;
                bf16x8 a0 = *reinterpret_cast<const bf16x8*>(&KsB[krow * 64 + ((lg * 8) ^ swz)]);
                bf16x8 a1 = *reinterpret_cast<const bf16x8*>(&KsB[krow * 64 + ((32 + lg * 8) ^ swz)]);
#pragma unroll
                for (int qs = 0; qs < 2; ++qs) {
                    f32x4 tv = {};
                    tv = __builtin_amdgcn_mfma_f32_16x16x32_bf16(a0, aq[si][qs][0], tv, 0, 0, 0);
                    tv = __builtin_amdgcn_mfma_f32_16x16x32_bf16(a1, aq[si][qs][1], tv, 0, 0, 0);
                    sc[qs][nt] = tv;
                }
            }
            __builtin_amdgcn_s_setprio(0);

            s16x4 ap[2][4];
#pragma unroll
            for (int qs = 0; qs < 2; ++qs) {
                const int qrow = q0[si] + w * 32 + qs * 16 + lr;
                if (j0 + 63 > q0[si] + w * 32 + qs * 16) {
#pragma unroll
                    for (int nt = 0; nt < 4; ++nt)
#pragma unroll
                        for (int r = 0; r < 4; ++r) {
                            int kv = j0 + nt * 16 + lg * 4 + r;
                            if (kv > qrow) sc[qs][nt][r] = -1e30f;
                        }
                }
                float tmax = sc[qs][0][0];
#pragma unroll
                for (int nt = 0; nt < 4; ++nt)
#pragma unroll
                    for (int r = 0; r < 4; ++r) tmax = fmaxf(tmax, sc[qs][nt][r]);
                tmax = fmaxf(tmax, __shfl_xor(tmax, 16, 64));
                tmax = fmaxf(tmax, __shfl_xor(tmax, 32, 64));
                float mold = m_run[si][qs];
                if (!__all(tmax - mold <= 8.0f)) {
                    float mnew = fmaxf(mold, tmax);
                    float corr = exp2f(mold - mnew);
                    m_run[si][qs] = mnew;
                    l_run[si][qs] *= corr;
#pragma unroll
                    for (int r = 0; r < 4; ++r) {
                        float cr = __shfl(corr, (lane & 48) | (lg * 4 + r), 64);
#pragma unroll
                        for (int dt = 0; dt < 4; ++dt) acc[si][qs][dt][r] *= cr;
                    }
                }
                float mnow = m_run[si][qs];
                float rs = 0.f;
#pragma unroll
                for (int nt = 0; nt < 4; ++nt)
#pragma unroll
                    for (int r = 0; r < 4; ++r) {
                        float p = exp2f(sc[qs][nt][r] - mnow);
                        rs += p;
                        ap[qs][nt][r] = f2bf_s(p);
                    }
                rs += __shfl_xor(rs, 16, 64);
                rs += __shfl_xor(rs, 32, 64);
                l_run[si][qs] += rs;
            }

            // PV: A = P (in-register), B = V^T slices (4-way b64 reads, BW floor)
            __builtin_amdgcn_s_setprio(1);
#pragma unroll
            for (int dt = 0; dt < 4; ++dt) {
                int vrow = dt * 16 + lr;
                int vswz = (((vrow & 7) ^ (vrow >> 3)) & 7) << 3;
                s16x4 bv[4];
#pragma unroll
                for (int nt = 0; nt < 4; ++nt)
                    bv[nt] = *reinterpret_cast<const s16x4*>(&VtB[vrow * 64 + ((nt * 16 + lg * 4) ^ vswz)]);
#pragma unroll
                for (int qs = 0; qs < 2; ++qs)
#pragma unroll
                    for (int nt = 0; nt < 4; ++nt)
                        acc[si][qs][dt] = mfma16(ap[qs][nt], bv[nt], acc[si][qs][dt]);
            }
            __builtin_amdgcn_s_setprio(0);
        }
    }

    // epilogue
#pragma unroll
    for (int si = 0; si < 2; ++si)
#pragma unroll
        for (int qs = 0; qs < 2; ++qs) {
            float inv = __builtin_amdgcn_rcpf(l_run[si][qs]);
#pragma unroll
            for (int r = 0; r < 4; ++r) {
                float invr = __shfl(inv, (lane & 48) | (lg * 4 + r), 64);
                int row = q0[si] + w * 32 + qs * 16 + lg * 4 + r;
#pragma unroll
                for (int dt = 0; dt < 4; ++dt)
                    O[base + (size_t)row * D_ + dt * 16 + lr] = (bf16)(acc[si][qs][dt][r] * invr);
            }
        }
}

// ---------------- launcher ----------------
extern "C" void kernel_launch(void* const* d_in, const int* in_sizes, int n_in,
                              void* d_out, int out_size, void* d_ws, size_t ws_size,
                              hipStream_t stream) {
    const float* x  = (const float*)d_in[0];
    const int*   tp = (const int*)d_in[1];
    const float* wq = (const float*)d_in[2];
    const float* wk = (const float*)d_in[3];
    const float* wv = (const float*)d_in[4];
    const float* wo = (const float*)d_in[5];

    bf16* ws = (bf16*)d_ws;
    bf16* Xbf = ws;
    bf16* Wqb = Xbf + (size_t)NTOK * D_;
    bf16* Wkb = Wqb + (size_t)D_ * D_;
    bf16* Wvb = Wkb + (size_t)D_ * D_;
    bf16* Wob = Wvb + (size_t)D_ * D_;
    bf16* Qr  = Wob + (size_t)D_ * D_;
    bf16* Kb  = Qr + (size_t)NTOK * D_;
    bf16* Vb  = Kb + (size_t)NTOK * D_;
    bf16* AO  = Vb + (size_t)NTOK * D_;
    float2* tab = (float2*)(AO + (size_t)NTOK * D_);
    (void)ws_size; (void)in_sizes; (void)n_in; (void)out_size;

    {
        int ntot8 = (NTOK * D_ + 4 * D_ * D_) / 8;
        cvt_all<<<(ntot8 + 255) / 256, 256, 0, stream>>>(x, wq, wk, wv, wo, Xbf);
    }
    rope_table<<<(NTOK * 32 + 255) / 256, 256, 0, stream>>>(tp, tab);

    gemm_qkv<<<dim3(NTOK / 128, 24), 256, 0, stream>>>(Xbf, Wqb, Wkb, Wvb, Qr, tab);

    flash_attn5<<<dim3(8, B_ * H_), 256, 0, stream>>>(Qr, Kb, Vb, AO);

    gemm_out<<<dim3(NTOK / 128, D_ / 128), 256, 0, stream>>>(AO, Wob, (float*)d_out);
}

// Round 6
// 208.842 us; speedup vs baseline: 2.1128x; 1.1386x over previous
//
#include <hip/hip_runtime.h>
#include <hip/hip_bf16.h>
#include <cstdint>
#include <cstddef>

#define B_ 4
#define S_ 2048
#define D_ 1024
#define H_ 16
#define DK_ 64
#define NTOK (B_*S_)

typedef __bf16 bf16;
typedef __bf16 bf16x8 __attribute__((ext_vector_type(8)));
typedef short s16x4 __attribute__((ext_vector_type(4)));
typedef float f32x4 __attribute__((ext_vector_type(4)));

#define AS1 __attribute__((address_space(1)))
#define AS3 __attribute__((address_space(3)))

static __device__ __forceinline__ short f2bf_s(float f) {
    return __builtin_bit_cast(short, (__bf16)f);
}

static __device__ __forceinline__ f32x4 mfma16(s16x4 a, s16x4 b, f32x4 c) {
#if __has_builtin(__builtin_amdgcn_mfma_f32_16x16x16bf16_1k)
    return __builtin_amdgcn_mfma_f32_16x16x16bf16_1k(a, b, c, 0, 0, 0);
#else
    asm volatile("v_mfma_f32_16x16x16_bf16 %0, %1, %2, %0\n\ts_nop 7\n\ts_nop 7"
                 : "+v"(c) : "v"(a), "v"(b));
    return c;
#endif
}

// ---------------- fused fp32 -> bf16 convert: [X | Wq | Wk | Wv | Wo] ----------------
__global__ void cvt_all(const float* __restrict__ x, const float* __restrict__ wq,
                        const float* __restrict__ wk, const float* __restrict__ wv,
                        const float* __restrict__ wo, bf16* __restrict__ dst) {
    const int NX8 = NTOK * D_ / 8;
    const int W8 = D_ * D_ / 8;          // 131072 = 2^17
    int i = blockIdx.x * blockDim.x + threadIdx.x;
    if (i >= NX8 + 4 * W8) return;
    const float* src; int j;
    if (i < NX8) { src = x; j = i; }
    else {
        int k = i - NX8;
        int w = k >> 17;
        j = k & (W8 - 1);
        src = w == 0 ? wq : (w == 1 ? wk : (w == 2 ? wv : wo));
    }
    const float4* s4 = reinterpret_cast<const float4*>(src) + (size_t)j * 2;
    float4 a = s4[0], b = s4[1];
    bf16x8 o;
    o[0] = (bf16)a.x; o[1] = (bf16)a.y; o[2] = (bf16)a.z; o[3] = (bf16)a.w;
    o[4] = (bf16)b.x; o[5] = (bf16)b.y; o[6] = (bf16)b.z; o[7] = (bf16)b.w;
    reinterpret_cast<bf16x8*>(dst)[i] = o;
}

// ---------------- RoPE cos/sin table: [NTOK][32] float2 ----------------
__global__ void rope_table(const int* __restrict__ pos, float2* __restrict__ tab) {
    int i = blockIdx.x * blockDim.x + threadIdx.x;
    if (i >= NTOK * 32) return;
    int n = i >> 5, p = i & 31;
    float pf = (float)pos[n];
    float freq = powf(10000.0f, -(float)p * (1.0f / 32.0f));
    float ang = pf * freq;
    float s, c;
    sincosf(ang, &s, &c);
    tab[i] = make_float2(c, s);
}

// ---------------- 256x128 GEMM, counted-vmcnt pipeline ----------------
// C = A[8192][1024] @ Bw^T (Bw rows = C cols). 512 thr = 8 waves (2M x 4N).
// LDS: 2 bufs x (A 256x64 | B 128x64), 96 KB. Stage kt+1 before vmcnt(6) ->
// never drains mid-loop (T3+T4). LDS chunk-XOR swizzle via pre-swizzled
// GLOBAL source + swizzled ds_read (linear gload_lds dest; rule #21).
// MODE 1: bf16 out, col-range selects {Q:RoPE+scale, K:RoPE, V:plain}.
// MODE 2: fp32 out.
template<int MODE>
__global__ __launch_bounds__(512, 2)
void gemm256(const bf16* __restrict__ A, const bf16* __restrict__ Bw,
             void* __restrict__ OutP, const float2* __restrict__ tab) {
    const float SCL2E = 0.125f * 1.44269504088896340736f;
    constexpr int NKT = 16;                       // K/64
    __shared__ alignas(16) bf16 lds[2][(256 + 128) * 64];
    const int tid = threadIdx.x;
    const int lane = tid & 63;
    const int wid = tid >> 6;
    const int wm = wid >> 2;                      // 0..1
    const int wn = wid & 3;                       // 0..3
    const int lr = lane & 15, lg = lane >> 4;
    const int m0 = blockIdx.x * 256;
    const int n0g = blockIdx.y * 128;             // global col (spans 3072 for QKV)

    f32x4 acc[8][2] = {};

    // stage K-tile kt into lds[bufi]: A = 4 units, B = 2 units, 16B/thread/unit.
    auto stage = [&](int kt, int bufi) {
        bf16* dst = &lds[bufi][0];
#pragma unroll
        for (int j = 0; j < 4; ++j) {
            int flat = j * 512 + tid;
            int r = flat >> 3, c = flat & 7;
            const bf16* src = A + (size_t)(m0 + r) * 1024 + kt * 64 + ((c ^ (r & 7)) << 3);
            __builtin_amdgcn_global_load_lds((const AS1 uint32_t*)src,
                                             (AS3 uint32_t*)(dst + (size_t)flat * 8), 16, 0, 0);
        }
#pragma unroll
        for (int j = 0; j < 2; ++j) {
            int f2 = j * 512 + tid;
            int r = f2 >> 3, c = f2 & 7;
            const bf16* src = Bw + (size_t)(n0g + r) * 1024 + kt * 64 + ((c ^ (r & 7)) << 3);
            __builtin_amdgcn_global_load_lds((const AS1 uint32_t*)src,
                                             (AS3 uint32_t*)(dst + 256 * 64 + (size_t)f2 * 8), 16, 0, 0);
        }
    };

    stage(0, 0);

    for (int kt = 0; kt < NKT; ++kt) {
        const bf16* bufA = &lds[kt & 1][0];
        const bf16* bufB = bufA + 256 * 64;

        asm volatile("" ::: "memory");
        __builtin_amdgcn_s_barrier();             // BAR-A: reads of buf[(kt+1)&1] done
        asm volatile("" ::: "memory");
        if (kt + 1 < NKT) {
            stage(kt + 1, (kt + 1) & 1);
            asm volatile("s_waitcnt vmcnt(6)" ::: "memory");   // kt's 6 landed; 6 in flight
        } else {
            asm volatile("s_waitcnt vmcnt(0)" ::: "memory");
        }
        __builtin_amdgcn_s_barrier();             // BAR-B: buf[kt&1] valid for all
        asm volatile("" ::: "memory");

        const int sx = lr & 7;                    // row&7 for all our read rows
        bf16x8 af[4][2], bfr[2][2];
        // ph1: A m0-3 + B n0; MFMA quadrant (m0-3, n0)
#pragma unroll
        for (int mf = 0; mf < 4; ++mf)
#pragma unroll
            for (int kh = 0; kh < 2; ++kh)
                af[mf][kh] = *reinterpret_cast<const bf16x8*>(
                    &bufA[(wm * 128 + mf * 16 + lr) * 64 + (((kh * 4 + lg) ^ sx) << 3)]);
#pragma unroll
        for (int kh = 0; kh < 2; ++kh)
            bfr[0][kh] = *reinterpret_cast<const bf16x8*>(
                &bufB[(wn * 32 + lr) * 64 + (((kh * 4 + lg) ^ sx) << 3)]);
#pragma unroll
        for (int mf = 0; mf < 4; ++mf)
#pragma unroll
            for (int kh = 0; kh < 2; ++kh)
                acc[mf][0] = __builtin_amdgcn_mfma_f32_16x16x32_bf16(af[mf][kh], bfr[0][kh], acc[mf][0], 0, 0, 0);
        // ph2: B n1; MFMA (m0-3, n1)
#pragma unroll
        for (int kh = 0; kh < 2; ++kh)
            bfr[1][kh] = *reinterpret_cast<const bf16x8*>(
                &bufB[(wn * 32 + 16 + lr) * 64 + (((kh * 4 + lg) ^ sx) << 3)]);
#pragma unroll
        for (int mf = 0; mf < 4; ++mf)
#pragma unroll
            for (int kh = 0; kh < 2; ++kh)
                acc[mf][1] = __builtin_amdgcn_mfma_f32_16x16x32_bf16(af[mf][kh], bfr[1][kh], acc[mf][1], 0, 0, 0);
        // ph3: A m4-7; MFMA (m4-7, n0)
#pragma unroll
        for (int mf = 0; mf < 4; ++mf)
#pragma unroll
            for (int kh = 0; kh < 2; ++kh)
                af[mf][kh] = *reinterpret_cast<const bf16x8*>(
                    &bufA[(wm * 128 + 64 + mf * 16 + lr) * 64 + (((kh * 4 + lg) ^ sx) << 3)]);
#pragma unroll
        for (int mf = 0; mf < 4; ++mf)
#pragma unroll
            for (int kh = 0; kh < 2; ++kh)
                acc[4 + mf][0] = __builtin_amdgcn_mfma_f32_16x16x32_bf16(af[mf][kh], bfr[0][kh], acc[4 + mf][0], 0, 0, 0);
        // ph4: MFMA (m4-7, n1)
#pragma unroll
        for (int mf = 0; mf < 4; ++mf)
#pragma unroll
            for (int kh = 0; kh < 2; ++kh)
                acc[4 + mf][1] = __builtin_amdgcn_mfma_f32_16x16x32_bf16(af[mf][kh], bfr[1][kh], acc[4 + mf][1], 0, 0, 0);
    }

    // epilogue: C layout col=lane&15, row=(lane>>4)*4+reg
#pragma unroll
    for (int mf = 0; mf < 8; ++mf) {
#pragma unroll
        for (int nf = 0; nf < 2; ++nf) {
#pragma unroll
            for (int r = 0; r < 4; ++r) {
                int row = m0 + wm * 128 + mf * 16 + lg * 4 + r;
                int colg = n0g + wn * 32 + nf * 16 + lr;
                float v = acc[mf][nf][r];
                if (MODE == 2) {
                    ((float*)OutP)[(size_t)row * 1024 + colg] = v;
                } else {
                    int which = colg >> 10;          // block-uniform (128 | 1024)
                    int col = colg & 1023;
                    bf16* O = (bf16*)OutP + (size_t)which * NTOK * D_;
                    if (which < 2) {
                        float partner = __shfl_xor(v, 1, 64);
                        float2 cs = tab[(size_t)row * 32 + ((col >> 1) & 31)];
                        float o = (col & 1) ? fmaf(v, cs.x, partner * cs.y)
                                            : fmaf(v, cs.x, -partner * cs.y);
                        if (which == 0) o *= SCL2E;
                        O[(size_t)row * D_ + col] = (bf16)o;
                    } else {
                        O[(size_t)row * D_ + col] = (bf16)v;
                    }
                }
            }
        }
    }
}

// ---------------- causal flash attention (unchanged from R5) ----------------
__global__ __launch_bounds__(256, 2)
void flash_attn5(const bf16* __restrict__ Q, const bf16* __restrict__ Kr,
                 const bf16* __restrict__ V, bf16* __restrict__ O) {
    __shared__ bf16 Ks[2][64 * 64];
    __shared__ bf16 Vt[2][64 * 64];
    const int tid = threadIdx.x, lane = tid & 63, w = tid >> 6;
    const int lr = lane & 15, lg = lane >> 4;
    const int qtA = blockIdx.x;
    const int qtB = 15 - qtA;
    const int q0[2] = { qtA * 128, qtB * 128 };
    const int ntS[2] = { 2 * qtA + 2, 2 * qtB + 2 };
    const int NT = ntS[1];
    const int bh = blockIdx.y;
    const int b = bh >> 4, h = bh & 15;
    const size_t base = ((size_t)b * S_) * D_ + (size_t)h * DK_;

    bf16x8 aq[2][2][2];
#pragma unroll
    for (int si = 0; si < 2; ++si)
#pragma unroll
        for (int qs = 0; qs < 2; ++qs) {
            int qrow = q0[si] + w * 32 + qs * 16 + lr;
            const bf16* qp = Q + base + (size_t)qrow * D_ + lg * 8;
            aq[si][qs][0] = *reinterpret_cast<const bf16x8*>(qp);
            aq[si][qs][1] = *reinterpret_cast<const bf16x8*>(qp + 32);
        }

    f32x4 acc[2][2][4] = {};
    float m_run[2][2] = {{-1e30f, -1e30f}, {-1e30f, -1e30f}};
    float l_run[2][2] = {{0.f, 0.f}, {0.f, 0.f}};

    const int sjj = tid >> 3;
    const int se0 = (tid & 7) * 8;
    const int vx = tid & 7;
    bf16x8 kreg[2], vreg[2];
#pragma unroll
    for (int i = 0; i < 2; ++i) {
        int row = sjj + i * 32;
        kreg[i] = *reinterpret_cast<const bf16x8*>(&Kr[base + (size_t)row * D_ + se0]);
        vreg[i] = *reinterpret_cast<const bf16x8*>(&V [base + (size_t)row * D_ + se0]);
    }

    for (int t = 0; t < NT; ++t) {
        const int j0 = t * 64;
        bf16* KsB = Ks[t & 1];
        bf16* VtB = Vt[t & 1];
#pragma unroll
        for (int i = 0; i < 2; ++i) {
            int jj = sjj + i * 32;
            *reinterpret_cast<bf16x8*>(&KsB[jj * 64 + (se0 ^ ((jj & 7) << 3))]) = kreg[i];
#pragma unroll
            for (int q = 0; q < 8; ++q) {
                int dd = se0 + q;
                int vswz = ((q ^ vx) & 7) << 3;
                VtB[dd * 64 + (jj ^ vswz)] = vreg[i][q];
            }
        }
        if (t + 1 < NT) {
#pragma unroll
            for (int i = 0; i < 2; ++i) {
                int row = (t + 1) * 64 + sjj + i * 32;
                kreg[i] = *reinterpret_cast<const bf16x8*>(&Kr[base + (size_t)row * D_ + se0]);
                vreg[i] = *reinterpret_cast<const bf16x8*>(&V [base + (size_t)row * D_ + se0]);
            }
        }
        __syncthreads();

#pragma unroll
        for (int si = 0; si < 2; ++si) {
            if (t >= ntS[si]) continue;
            const int qmaxw = q0[si] + w * 32 + 31;
            if (j0 > qmaxw) continue;

            f32x4 sc[2][4];
            __builtin_amdgcn_s_setprio(1);
#pragma unroll
            for (int nt = 0; nt < 4; ++nt) {
                int krow = nt * 16 + lr;
                int swz = (krow & 7) << 3;
                bf16x8 a0 = *reinterpret_cast<const bf16x8*>(&KsB[krow * 64 + ((lg * 8) ^ swz)]);
                bf16x8 a1 = *reinterpret_cast<const bf16x8*>(&KsB[krow * 64 + ((32 + lg * 8) ^ swz)]);
#pragma unroll
                for (int qs = 0; qs < 2; ++qs) {
                    f32x4 tv = {};
                    tv = __builtin_amdgcn_mfma_f32_16x16x32_bf16(a0, aq[si][qs][0], tv, 0, 0, 0);
                    tv = __builtin_amdgcn_mfma_f32_16x16x32_bf16(a1, aq[si][qs][1], tv, 0, 0, 0);
                    sc[qs][nt] = tv;
                }
            }
            __builtin_amdgcn_s_setprio(0);

            s16x4 ap[2][4];
#pragma unroll
            for (int qs = 0; qs < 2; ++qs) {
                const int qrow = q0[si] + w * 32 + qs * 16 + lr;
                if (j0 + 63 > q0[si] + w * 32 + qs * 16) {
#pragma unroll
                    for (int nt = 0; nt < 4; ++nt)
#pragma unroll
                        for (int r = 0; r < 4; ++r) {
                            int kv = j0 + nt * 16 + lg * 4 + r;
                            if (kv > qrow) sc[qs][nt][r] = -1e30f;
                        }
                }
                float tmax = sc[qs][0][0];
#pragma unroll
                for (int nt = 0; nt < 4; ++nt)
#pragma unroll
                    for (int r = 0; r < 4; ++r) tmax = fmaxf(tmax, sc[qs][nt][r]);
                tmax = fmaxf(tmax, __shfl_xor(tmax, 16, 64));
                tmax = fmaxf(tmax, __shfl_xor(tmax, 32, 64));
                float mold = m_run[si][qs];
                if (!__all(tmax - mold <= 8.0f)) {
                    float mnew = fmaxf(mold, tmax);
                    float corr = exp2f(mold - mnew);
                    m_run[si][qs] = mnew;
                    l_run[si][qs] *= corr;
#pragma unroll
                    for (int r = 0; r < 4; ++r) {
                        float cr = __shfl(corr, (lane & 48) | (lg * 4 + r), 64);
#pragma unroll
                        for (int dt = 0; dt < 4; ++dt) acc[si][qs][dt][r] *= cr;
                    }
                }
                float mnow = m_run[si][qs];
                float rs = 0.f;
#pragma unroll
                for (int nt = 0; nt < 4; ++nt)
#pragma unroll
                    for (int r = 0; r < 4; ++r) {
                        float p = exp2f(sc[qs][nt][r] - mnow);
                        rs += p;
                        ap[qs][nt][r] = f2bf_s(p);
                    }
                rs += __shfl_xor(rs, 16, 64);
                rs += __shfl_xor(rs, 32, 64);
                l_run[si][qs] += rs;
            }

            __builtin_amdgcn_s_setprio(1);
#pragma unroll
            for (int dt = 0; dt < 4; ++dt) {
                int vrow = dt * 16 + lr;
                int vswz = (((vrow & 7) ^ (vrow >> 3)) & 7) << 3;
                s16x4 bv[4];
#pragma unroll
                for (int nt = 0; nt < 4; ++nt)
                    bv[nt] = *reinterpret_cast<const s16x4*>(&VtB[vrow * 64 + ((nt * 16 + lg * 4) ^ vswz)]);
#pragma unroll
                for (int qs = 0; qs < 2; ++qs)
#pragma unroll
                    for (int nt = 0; nt < 4; ++nt)
                        acc[si][qs][dt] = mfma16(ap[qs][nt], bv[nt], acc[si][qs][dt]);
            }
            __builtin_amdgcn_s_setprio(0);
        }
    }

#pragma unroll
    for (int si = 0; si < 2; ++si)
#pragma unroll
        for (int qs = 0; qs < 2; ++qs) {
            float inv = __builtin_amdgcn_rcpf(l_run[si][qs]);
#pragma unroll
            for (int r = 0; r < 4; ++r) {
                float invr = __shfl(inv, (lane & 48) | (lg * 4 + r), 64);
                int row = q0[si] + w * 32 + qs * 16 + lg * 4 + r;
#pragma unroll
                for (int dt = 0; dt < 4; ++dt)
                    O[base + (size_t)row * D_ + dt * 16 + lr] = (bf16)(acc[si][qs][dt][r] * invr);
            }
        }
}

// ---------------- launcher ----------------
extern "C" void kernel_launch(void* const* d_in, const int* in_sizes, int n_in,
                              void* d_out, int out_size, void* d_ws, size_t ws_size,
                              hipStream_t stream) {
    const float* x  = (const float*)d_in[0];
    const int*   tp = (const int*)d_in[1];
    const float* wq = (const float*)d_in[2];
    const float* wk = (const float*)d_in[3];
    const float* wv = (const float*)d_in[4];
    const float* wo = (const float*)d_in[5];

    bf16* ws = (bf16*)d_ws;
    bf16* Xbf = ws;
    bf16* Wqb = Xbf + (size_t)NTOK * D_;          // [3072][1024] packed Wq|Wk|Wv
    bf16* Wkb = Wqb + (size_t)D_ * D_;
    bf16* Wvb = Wkb + (size_t)D_ * D_;
    bf16* Wob = Wvb + (size_t)D_ * D_;
    bf16* Qr  = Wob + (size_t)D_ * D_;
    bf16* Kb  = Qr + (size_t)NTOK * D_;
    bf16* Vb  = Kb + (size_t)NTOK * D_;
    bf16* AO  = Vb + (size_t)NTOK * D_;
    float2* tab = (float2*)(AO + (size_t)NTOK * D_);
    (void)ws_size; (void)in_sizes; (void)n_in; (void)out_size;
    (void)Wkb; (void)Wvb;

    {
        int ntot8 = (NTOK * D_ + 4 * D_ * D_) / 8;
        cvt_all<<<(ntot8 + 255) / 256, 256, 0, stream>>>(x, wq, wk, wv, wo, Xbf);
    }
    rope_table<<<(NTOK * 32 + 255) / 256, 256, 0, stream>>>(tp, tab);

    // QKV: one GEMM vs packed [3072][1024] weights; grid 32x24 = 768 blocks
    gemm256<1><<<dim3(NTOK / 256, 24), 512, 0, stream>>>(Xbf, Wqb, Qr, tab);

    flash_attn5<<<dim3(8, B_ * H_), 256, 0, stream>>>(Qr, Kb, Vb, AO);

    // out-projection: grid 32x8 = 256 blocks, fp32 out
    gemm256<2><<<dim3(NTOK / 256, D_ / 128), 512, 0, stream>>>(AO, Wob, d_out, nullptr);
}